// Round 17
// baseline (181.666 us; speedup 1.0000x reference)
//
#include <hip/hip_runtime.h>

#define NB 4
#define NT 2048
#define ND 1024
#define NH 16
#define DHD 64
#define KVB 256

typedef __attribute__((ext_vector_type(4))) float f32x4;
typedef __attribute__((ext_vector_type(16))) float f32x16;
typedef __attribute__((ext_vector_type(8))) short bf16x8;
typedef __attribute__((ext_vector_type(4))) short s16x4;

__device__ __forceinline__ short tobf(float f) {
    union { __bf16 b; short s; } u; u.b = (__bf16)f; return u.s;
}

__device__ __forceinline__ float fexp2(float x) {
#if __has_builtin(__builtin_amdgcn_exp2f)
    return __builtin_amdgcn_exp2f(x);
#else
    return exp2f(x);
#endif
}

// async global->LDS, 16B per lane; lds dest is wave-uniform base + lane*16
__device__ __forceinline__ void gload16(const short* g, short* l) {
    __builtin_amdgcn_global_load_lds(
        (const __attribute__((address_space(1))) void*)g,
        (__attribute__((address_space(3))) void*)l, 16, 0, 0);
}

// Q pre-scale: (1/sqrt(64)) * log2(e)  -> softmax runs in exp2 domain
#define QSCALE 0.18033688011112042f

// ---------------- K0a: x f32 -> bf16 ----------------
__global__ __launch_bounds__(256)
void cvt_kernel(const float* __restrict__ x, short* __restrict__ xb) {
    size_t i = (size_t)blockIdx.x * 256 + threadIdx.x;
    float4 a = *reinterpret_cast<const float4*>(x + i * 8);
    float4 b = *reinterpret_cast<const float4*>(x + i * 8 + 4);
    bf16x8 o;
    o[0] = tobf(a.x); o[1] = tobf(a.y); o[2] = tobf(a.z); o[3] = tobf(a.w);
    o[4] = tobf(b.x); o[5] = tobf(b.y); o[6] = tobf(b.z); o[7] = tobf(b.w);
    *reinterpret_cast<bf16x8*>(xb + i * 8) = o;
}

// ---------------- K0b: W f32 [k][n] -> bf16 W^T [n][k] (z selects among 4 sources) ----------------
__global__ __launch_bounds__(256)
void cvtw_kernel(const float* __restrict__ W0, const float* __restrict__ W1,
                 const float* __restrict__ W2, const float* __restrict__ W3,
                 short* __restrict__ Wt) {
    const int z = blockIdx.z;
    const float* W = (z == 0) ? W0 : (z == 1) ? W1 : (z == 2) ? W2 : W3;
    short* dst = Wt + (size_t)z * ND * ND;
    const int tid = threadIdx.x;
    const int kc = tid & 7;
    const int n0 = blockIdx.x * 128 + ((tid >> 3) & 31) * 4;
    const int kb = blockIdx.y * 64;
    float4 v[8];
#pragma unroll
    for (int s = 0; s < 8; ++s)
        v[s] = *reinterpret_cast<const float4*>(W + (size_t)(kb + kc * 8 + s) * ND + n0);
    const float* vp = reinterpret_cast<const float*>(v);
#pragma unroll
    for (int j = 0; j < 4; ++j) {
        bf16x8 hv;
#pragma unroll
        for (int s = 0; s < 8; ++s) hv[s] = tobf(vp[s * 4 + j]);
        *reinterpret_cast<bf16x8*>(dst + (size_t)(n0 + j) * ND + kb + kc * 8) = hv;
    }
}

// ======================= GEMM kernels: both operands via global_load_lds =======================

// ---------------- K1: QKV projections (A = xb bf16, B = Wt bf16) ----------------
__global__ __launch_bounds__(256, 4)
void qkv_kernel(const short* __restrict__ xb, const short* __restrict__ Wt,
                short* __restrict__ Qo, short* __restrict__ Ko, short* __restrict__ Vo)
{
    const int i = blockIdx.x;            // 0..1535
    const int xcd = i & 7, c = i >> 3;   // c 0..191
    const int z = c >> 6, r = c & 63;
    const int by = xcd * 8 + (r >> 3);
    const int bx = r & 7;

    const short* W = Wt + (size_t)z * ND * ND;
    short* Out = (z == 0) ? Qo : (z == 1) ? Ko : Vo;
    const float oscale = (z == 0) ? QSCALE : 1.0f;

    __shared__ short As[128 * 64];
    __shared__ short Bs[128 * 64];

    const int tid = threadIdx.x;
    const int lane = tid & 63;
    const int wave = tid >> 6;
    const int row16 = lane & 15;
    const int grp = lane >> 4;
    const int mbase = by * 128;
    const int nbase = bx * 128;
    const int wm = (wave >> 1) * 64;
    const int wn = (wave & 1) * 64;
    const int srcc = ((lane & 7) ^ (lane >> 3)) * 8;
    const int lrow = lane >> 3;

    f32x4 acc[4][4];
#pragma unroll
    for (int a = 0; a < 4; ++a)
#pragma unroll
        for (int bq = 0; bq < 4; ++bq) acc[a][bq] = (f32x4)0.0f;

    for (int kb = 0; kb < ND; kb += 64) {
        __syncthreads();
#pragma unroll
        for (int it = 0; it < 4; ++it) {
            int seg = wave * 4 + it;
            int row = seg * 8 + lrow;
            gload16(xb + (size_t)(mbase + row) * ND + kb + srcc, As + seg * 512);
            gload16(W  + (size_t)(nbase + row) * ND + kb + srcc, Bs + seg * 512);
        }
        __syncthreads();

#pragma unroll
        for (int kk = 0; kk < 2; ++kk) {
            const int c8 = kk * 4 + grp;
            bf16x8 af[4], bfr[4];
#pragma unroll
            for (int mi = 0; mi < 4; ++mi) {
                int row = wm + mi * 16 + row16;
                af[mi] = *reinterpret_cast<const bf16x8*>(&As[row * 64 + ((c8 ^ (row & 7)) * 8)]);
            }
#pragma unroll
            for (int ni = 0; ni < 4; ++ni) {
                int n = wn + ni * 16 + row16;
                bfr[ni] = *reinterpret_cast<const bf16x8*>(&Bs[n * 64 + ((c8 ^ (n & 7)) * 8)]);
            }
            __builtin_amdgcn_s_setprio(1);
#pragma unroll
            for (int mi = 0; mi < 4; ++mi)
#pragma unroll
                for (int ni = 0; ni < 4; ++ni)
                    acc[mi][ni] = __builtin_amdgcn_mfma_f32_16x16x32_bf16(af[mi], bfr[ni], acc[mi][ni], 0, 0, 0);
            __builtin_amdgcn_s_setprio(0);
        }
    }

#pragma unroll
    for (int mi = 0; mi < 4; ++mi)
#pragma unroll
        for (int ni = 0; ni < 4; ++ni)
#pragma unroll
            for (int rr = 0; rr < 4; ++rr) {
                int rowg = mbase + wm + mi * 16 + grp * 4 + rr;
                int colg = nbase + wn + ni * 16 + row16;
                int b = rowg >> 11, t = rowg & (NT - 1);
                int h = colg >> 6, d = colg & 63;
                Out[((size_t)(b * NH + h) * NT + t) * DHD + d] = tobf(acc[mi][ni][rr] * oscale);
            }
}

// ---------------- K2: flash attention — 8 waves, KVB=256, balanced staging ----------------
// Staging per tile: K = 4 reg-chunks/thread (all waves); V = 4 quad-loads + 8 b64 writes,
// spread across ALL 512 threads (vi = tid&63 covers kv-quads 0..63, vdc = tid>>6 covers d-chunks).
__global__ __launch_bounds__(512)
void attn_kernel(const short* __restrict__ Qg, const short* __restrict__ Kg,
                 const short* __restrict__ Vg, short* __restrict__ An)
{
    __shared__ short Ks[KVB * 64];     // [256 kv][64 d]
    __shared__ short Vs[64 * KVB];     // [64 d][256 kv]

    const int tid = threadIdx.x;
    const int lane = tid & 63;
    const int wave = tid >> 6;       // 0..7
    const int l31 = lane & 31;
    const int h = lane >> 5;

    const int id = blockIdx.x;       // 0..511
    const int slot = id >> 3;        // 0..63
    const int bh = (id & 7) * 8 + (slot & 7);
    const int qbase = (slot >> 3) * 256;

    const int b = bh >> 4, hh = bh & 15;
    const size_t headoff = (size_t)bh * NT * DHD;

    bf16x8 qf[4];
    {
        const short* qp = Qg + headoff + (size_t)(qbase + wave * 32 + l31) * DHD + h * 8;
#pragma unroll
        for (int ds = 0; ds < 4; ++ds)
            qf[ds] = *reinterpret_cast<const bf16x8*>(qp + ds * 16);
    }

    float l_run = 0.f;
    f32x16 o0 = (f32x16)0.f, o1 = (f32x16)0.f;

    bf16x8 Kst[4], Vst[4];
    const int vi = tid & 63, vdc = tid >> 6;   // kv-quad 4*vi (0..255), d-chunk vdc (0..7)

    // prologue: tile 0 -> regs
    {
        const short* Kp = Kg + headoff;
        const short* Vp = Vg + headoff;
#pragma unroll
        for (int it = 0; it < 4; ++it) {
            int chid = tid + it * 512;
            Kst[it] = *reinterpret_cast<const bf16x8*>(Kp + (size_t)(chid >> 3) * DHD + (chid & 7) * 8);
        }
#pragma unroll
        for (int s = 0; s < 4; ++s)
            Vst[s] = *reinterpret_cast<const bf16x8*>(Vp + (size_t)(4 * vi + s) * DHD + vdc * 8);
    }

#define QKT(SACC, ST) do {                                                              \
        SACC = (f32x16)0.f;                                                             \
        __builtin_amdgcn_s_setprio(1);                                                  \
        _Pragma("unroll")                                                               \
        for (int ds = 0; ds < 4; ++ds) {                                                \
            int row_ = (ST) * 32 + l31;                                                 \
            int c8_ = ds * 2 + h;                                                       \
            bf16x8 kf_ = *reinterpret_cast<const bf16x8*>(                              \
                &Ks[row_ * 64 + ((c8_ ^ (row_ & 7)) * 8)]);                             \
            SACC = __builtin_amdgcn_mfma_f32_32x32x16_bf16(kf_, qf[ds], SACC, 0, 0, 0); \
        }                                                                               \
        __builtin_amdgcn_s_setprio(0);                                                  \
    } while (0)

#define SMPV(SACC, ST) do {                                                             \
        float p_[16];                                                                   \
        float rs_ = 0.f;                                                                \
        _Pragma("unroll")                                                               \
        for (int j = 0; j < 16; ++j) { p_[j] = fexp2(SACC[j]); rs_ += p_[j]; }          \
        l_run += rs_;                                                                   \
        union Pair_ { s16x4 v; int w[2]; };                                             \
        Pair_ quad_[2][2];                                                              \
        _Pragma("unroll")                                                               \
        for (int ks = 0; ks < 2; ++ks)                                                  \
            _Pragma("unroll")                                                           \
            for (int hd = 0; hd < 2; ++hd)                                              \
                _Pragma("unroll")                                                       \
                for (int e = 0; e < 4; ++e)                                             \
                    quad_[ks][hd].v[e] = tobf(p_[8 * ks + 4 * hd + e]);                 \
        bf16x8 pf_[2];                                                                  \
        _Pragma("unroll")                                                               \
        for (int ks = 0; ks < 2; ++ks) {                                                \
            Pair_ send_;                                                                \
            send_.v = h ? quad_[ks][0].v : quad_[ks][1].v;                              \
            Pair_ recv_;                                                                \
            recv_.w[0] = __shfl_xor(send_.w[0], 32);                                    \
            recv_.w[1] = __shfl_xor(send_.w[1], 32);                                    \
            Pair_ ownq_;                                                                \
            ownq_.v = h ? quad_[ks][1].v : quad_[ks][0].v;                              \
            union { struct { s16x4 lo, hi; } s; bf16x8 v; } u_;                         \
            u_.s.lo = h ? recv_.v : ownq_.v;                                            \
            u_.s.hi = h ? ownq_.v : recv_.v;                                            \
            pf_[ks] = u_.v;                                                             \
        }                                                                               \
        _Pragma("unroll")                                                               \
        for (int ks = 0; ks < 2; ++ks) {                                                \
            int ck_ = (ST) * 4 + ks * 2 + h;                                            \
            bf16x8 v0_ = *reinterpret_cast<const bf16x8*>(                              \
                &Vs[l31 * KVB + ((ck_ ^ (l31 & 7)) * 8)]);                              \
            bf16x8 v1_ = *reinterpret_cast<const bf16x8*>(                              \
                &Vs[(32 + l31) * KVB + ((ck_ ^ (l31 & 7)) * 8)]);                       \
            __builtin_amdgcn_s_setprio(1);                                              \
            o0 = __builtin_amdgcn_mfma_f32_32x32x16_bf16(pf_[ks], v0_, o0, 0, 0, 0);    \
            o1 = __builtin_amdgcn_mfma_f32_32x32x16_bf16(pf_[ks], v1_, o1, 0, 0, 0);    \
            __builtin_amdgcn_s_setprio(0);                                              \
        }                                                                               \
    } while (0)

    for (int kv = 0; kv < NT; kv += KVB) {
        // ---- (A): all reads of previous tile's LDS complete ----
        __builtin_amdgcn_sched_barrier(0);
        asm volatile("s_waitcnt lgkmcnt(0)" ::: "memory");
        __builtin_amdgcn_s_barrier();
        __builtin_amdgcn_sched_barrier(0);

        // commit staged regs -> LDS
#pragma unroll
        for (int it = 0; it < 4; ++it) {
            int chid = tid + it * 512;
            int row = chid >> 3, c8 = chid & 7;
            *reinterpret_cast<bf16x8*>(&Ks[row * 64 + ((c8 ^ (row & 7)) * 8)]) = Kst[it];
        }
#pragma unroll
        for (int e = 0; e < 8; ++e) {
            int d = vdc * 8 + e;
            s16x4 pk;
            pk[0] = Vst[0][e]; pk[1] = Vst[1][e]; pk[2] = Vst[2][e]; pk[3] = Vst[3][e];
            int kv4 = 4 * vi;
            *reinterpret_cast<s16x4*>(&Vs[d * KVB + (((kv4 >> 3) ^ (d & 7)) * 8) + (kv4 & 7)]) = pk;
        }
        // issue next-tile loads (in flight across compute)
        if (kv + KVB < NT) {
            const short* Kp = Kg + headoff + (size_t)(kv + KVB) * DHD;
            const short* Vp = Vg + headoff + (size_t)(kv + KVB) * DHD;
#pragma unroll
            for (int it = 0; it < 4; ++it) {
                int chid = tid + it * 512;
                Kst[it] = *reinterpret_cast<const bf16x8*>(Kp + (size_t)(chid >> 3) * DHD + (chid & 7) * 8);
            }
#pragma unroll
            for (int s = 0; s < 4; ++s)
                Vst[s] = *reinterpret_cast<const bf16x8*>(Vp + (size_t)(4 * vi + s) * DHD + vdc * 8);
        }

        // ---- (B): staged LDS visible ----
        __builtin_amdgcn_sched_barrier(0);
        asm volatile("s_waitcnt lgkmcnt(0)" ::: "memory");
        __builtin_amdgcn_s_barrier();
        __builtin_amdgcn_sched_barrier(0);

        // ---- 2-deep pipeline over 8 subtiles ----
        f32x16 sA, sB;
        QKT(sA, 0);
        QKT(sB, 1);
        SMPV(sA, 0);
        QKT(sA, 2);
        SMPV(sB, 1);
        QKT(sB, 3);
        SMPV(sA, 2);
        QKT(sA, 4);
        SMPV(sB, 3);
        QKT(sB, 5);
        SMPV(sA, 4);
        QKT(sA, 6);
        SMPV(sB, 5);
        QKT(sB, 7);
        SMPV(sA, 6);
        SMPV(sB, 7);
    }
#undef QKT
#undef SMPV

    // ---- epilogue: merge half-sums, normalize, store ----
    float lt = l_run + __shfl_xor(l_run, 32);
    float linv = 1.0f / lt;
#pragma unroll
    for (int j = 0; j < 16; ++j) {
        int qr = (j & 3) + 8 * (j >> 2) + 4 * h;
        float lq = __shfl(linv, qr);
        int t = qbase + wave * 32 + qr;
        short* orow = An + (size_t)(b * NT + t) * ND + hh * DHD;
        orow[l31] = tobf(o0[j] * lq);
        orow[32 + l31] = tobf(o1[j] * lq);
    }
}

// ---------------- K3: output projection + bias (global_load_lds both sides) ----------------
__global__ __launch_bounds__(256, 4)
void outproj_kernel(const short* __restrict__ An, const short* __restrict__ Wot,
                    const float* __restrict__ bo, float* __restrict__ out)
{
    const int i = blockIdx.x;            // 0..511
    const int xcd = i & 7, c = i >> 3;
    const int by = xcd * 8 + (c >> 3);
    const int bx = c & 7;

    __shared__ short As[128 * 64];
    __shared__ short Bs[128 * 64];

    const int tid = threadIdx.x;
    const int lane = tid & 63;
    const int wave = tid >> 6;
    const int row16 = lane & 15;
    const int grp = lane >> 4;
    const int mbase = by * 128;
    const int nbase = bx * 128;
    const int wm = (wave >> 1) * 64;
    const int wn = (wave & 1) * 64;
    const int srcc = ((lane & 7) ^ (lane >> 3)) * 8;
    const int lrow = lane >> 3;

    f32x4 acc[4][4];
#pragma unroll
    for (int a = 0; a < 4; ++a)
#pragma unroll
        for (int bq = 0; bq < 4; ++bq) acc[a][bq] = (f32x4)0.0f;

    for (int kb = 0; kb < ND; kb += 64) {
        __syncthreads();
#pragma unroll
        for (int it = 0; it < 4; ++it) {
            int seg = wave * 4 + it;
            int row = seg * 8 + lrow;
            gload16(An  + (size_t)(mbase + row) * ND + kb + srcc, As + seg * 512);
            gload16(Wot + (size_t)(nbase + row) * ND + kb + srcc, Bs + seg * 512);
        }
        __syncthreads();

#pragma unroll
        for (int kk = 0; kk < 2; ++kk) {
            const int c8 = kk * 4 + grp;
            bf16x8 af[4], bfr[4];
#pragma unroll
            for (int mi = 0; mi < 4; ++mi) {
                int row = wm + mi * 16 + row16;
                af[mi] = *reinterpret_cast<const bf16x8*>(&As[row * 64 + ((c8 ^ (row & 7)) * 8)]);
            }
#pragma unroll
            for (int ni = 0; ni < 4; ++ni) {
                int n = wn + ni * 16 + row16;
                bfr[ni] = *reinterpret_cast<const bf16x8*>(&Bs[n * 64 + ((c8 ^ (n & 7)) * 8)]);
            }
            __builtin_amdgcn_s_setprio(1);
#pragma unroll
            for (int mi = 0; mi < 4; ++mi)
#pragma unroll
                for (int ni = 0; ni < 4; ++ni)
                    acc[mi][ni] = __builtin_amdgcn_mfma_f32_16x16x32_bf16(af[mi], bfr[ni], acc[mi][ni], 0, 0, 0);
            __builtin_amdgcn_s_setprio(0);
        }
    }

#pragma unroll
    for (int ni = 0; ni < 4; ++ni) {
        int colg = nbase + wn + ni * 16 + row16;
        float bv = bo[colg];
#pragma unroll
        for (int mi = 0; mi < 4; ++mi)
#pragma unroll
            for (int rr = 0; rr < 4; ++rr) {
                int rowg = mbase + wm + mi * 16 + grp * 4 + rr;
                out[(size_t)rowg * ND + colg] = acc[mi][ni][rr] + bv;
            }
    }
}

extern "C" void kernel_launch(void* const* d_in, const int* in_sizes, int n_in,
                              void* d_out, int out_size, void* d_ws, size_t ws_size,
                              hipStream_t stream) {
    const float* x  = (const float*)d_in[0];
    const float* Wq = (const float*)d_in[1];
    const float* Wk = (const float*)d_in[2];
    const float* Wv = (const float*)d_in[3];
    const float* Wo = (const float*)d_in[4];
    const float* bo = (const float*)d_in[5];
    float* out = (float*)d_out;

    const size_t HSZ = (size_t)NB * NH * NT * DHD;
    short* Q  = (short*)d_ws;
    short* K  = Q + HSZ;
    short* V  = K + HSZ;
    short* At = V + HSZ;   // attn output; holds xb before attn runs
    short* xb = At;        // x (bf16) — dead once attn overwrites At
    short* Wt4 = (short*)d_out;           // W^T bf16 x4 (8.4 MB) — d_out scratch, overwritten by out
    short* Wot = Wt4 + (size_t)3 * ND * ND;

    cvt_kernel<<<dim3((NB * NT * ND) / (256 * 8)), dim3(256), 0, stream>>>(x, xb);
    cvtw_kernel<<<dim3(8, 16, 4), dim3(256), 0, stream>>>(Wq, Wk, Wv, Wo, Wt4);
    qkv_kernel<<<dim3(3 * 8 * 64), dim3(256), 0, stream>>>(xb, Wt4, Q, K, V);
    attn_kernel<<<dim3(512), dim3(512), 0, stream>>>(Q, K, V, At);
    outproj_kernel<<<dim3(8 * 64), dim3(256), 0, stream>>>(At, Wot, bo, out);
}

// Round 18
// 171.512 us; speedup vs baseline: 1.0592x; 1.0592x over previous
//
#include <hip/hip_runtime.h>

#define NB 4
#define NT 2048
#define ND 1024
#define NH 16
#define DHD 64
#define KVB 128

typedef __attribute__((ext_vector_type(4))) float f32x4;
typedef __attribute__((ext_vector_type(16))) float f32x16;
typedef __attribute__((ext_vector_type(8))) short bf16x8;
typedef __attribute__((ext_vector_type(4))) short s16x4;

__device__ __forceinline__ short tobf(float f) {
    union { __bf16 b; short s; } u; u.b = (__bf16)f; return u.s;
}

__device__ __forceinline__ float fexp2(float x) {
#if __has_builtin(__builtin_amdgcn_exp2f)
    return __builtin_amdgcn_exp2f(x);
#else
    return exp2f(x);
#endif
}

// async global->LDS, 16B per lane; lds dest is wave-uniform base + lane*16
__device__ __forceinline__ void gload16(const short* g, short* l) {
    __builtin_amdgcn_global_load_lds(
        (const __attribute__((address_space(1))) void*)g,
        (__attribute__((address_space(3))) void*)l, 16, 0, 0);
}

// Q pre-scale: (1/sqrt(64)) * log2(e)  -> softmax runs in exp2 domain
#define QSCALE 0.18033688011112042f

// ---------------- K0a: x f32 -> bf16 ----------------
__global__ __launch_bounds__(256)
void cvt_kernel(const float* __restrict__ x, short* __restrict__ xb) {
    size_t i = (size_t)blockIdx.x * 256 + threadIdx.x;
    float4 a = *reinterpret_cast<const float4*>(x + i * 8);
    float4 b = *reinterpret_cast<const float4*>(x + i * 8 + 4);
    bf16x8 o;
    o[0] = tobf(a.x); o[1] = tobf(a.y); o[2] = tobf(a.z); o[3] = tobf(a.w);
    o[4] = tobf(b.x); o[5] = tobf(b.y); o[6] = tobf(b.z); o[7] = tobf(b.w);
    *reinterpret_cast<bf16x8*>(xb + i * 8) = o;
}

// ---------------- K0b: W f32 [k][n] -> bf16 W^T [n][k] (z selects among 4 sources) ----------------
__global__ __launch_bounds__(256)
void cvtw_kernel(const float* __restrict__ W0, const float* __restrict__ W1,
                 const float* __restrict__ W2, const float* __restrict__ W3,
                 short* __restrict__ Wt) {
    const int z = blockIdx.z;
    const float* W = (z == 0) ? W0 : (z == 1) ? W1 : (z == 2) ? W2 : W3;
    short* dst = Wt + (size_t)z * ND * ND;
    const int tid = threadIdx.x;
    const int kc = tid & 7;
    const int n0 = blockIdx.x * 128 + ((tid >> 3) & 31) * 4;
    const int kb = blockIdx.y * 64;
    float4 v[8];
#pragma unroll
    for (int s = 0; s < 8; ++s)
        v[s] = *reinterpret_cast<const float4*>(W + (size_t)(kb + kc * 8 + s) * ND + n0);
    const float* vp = reinterpret_cast<const float*>(v);
#pragma unroll
    for (int j = 0; j < 4; ++j) {
        bf16x8 hv;
#pragma unroll
        for (int s = 0; s < 8; ++s) hv[s] = tobf(vp[s * 4 + j]);
        *reinterpret_cast<bf16x8*>(dst + (size_t)(n0 + j) * ND + kb + kc * 8) = hv;
    }
}

// ======================= GEMM kernels: both operands via global_load_lds =======================

// ---------------- K1: QKV projections (A = xb bf16, B = Wt bf16) ----------------
__global__ __launch_bounds__(256, 4)
void qkv_kernel(const short* __restrict__ xb, const short* __restrict__ Wt,
                short* __restrict__ Qo, short* __restrict__ Ko, short* __restrict__ Vo)
{
    const int i = blockIdx.x;            // 0..1535
    const int xcd = i & 7, c = i >> 3;   // c 0..191
    const int z = c >> 6, r = c & 63;
    const int by = xcd * 8 + (r >> 3);
    const int bx = r & 7;

    const short* W = Wt + (size_t)z * ND * ND;
    short* Out = (z == 0) ? Qo : (z == 1) ? Ko : Vo;
    const float oscale = (z == 0) ? QSCALE : 1.0f;

    __shared__ short As[128 * 64];
    __shared__ short Bs[128 * 64];

    const int tid = threadIdx.x;
    const int lane = tid & 63;
    const int wave = tid >> 6;
    const int row16 = lane & 15;
    const int grp = lane >> 4;
    const int mbase = by * 128;
    const int nbase = bx * 128;
    const int wm = (wave >> 1) * 64;
    const int wn = (wave & 1) * 64;
    const int srcc = ((lane & 7) ^ (lane >> 3)) * 8;
    const int lrow = lane >> 3;

    f32x4 acc[4][4];
#pragma unroll
    for (int a = 0; a < 4; ++a)
#pragma unroll
        for (int bq = 0; bq < 4; ++bq) acc[a][bq] = (f32x4)0.0f;

    for (int kb = 0; kb < ND; kb += 64) {
        __syncthreads();
#pragma unroll
        for (int it = 0; it < 4; ++it) {
            int seg = wave * 4 + it;
            int row = seg * 8 + lrow;
            gload16(xb + (size_t)(mbase + row) * ND + kb + srcc, As + seg * 512);
            gload16(W  + (size_t)(nbase + row) * ND + kb + srcc, Bs + seg * 512);
        }
        __syncthreads();

#pragma unroll
        for (int kk = 0; kk < 2; ++kk) {
            const int c8 = kk * 4 + grp;
            bf16x8 af[4], bfr[4];
#pragma unroll
            for (int mi = 0; mi < 4; ++mi) {
                int row = wm + mi * 16 + row16;
                af[mi] = *reinterpret_cast<const bf16x8*>(&As[row * 64 + ((c8 ^ (row & 7)) * 8)]);
            }
#pragma unroll
            for (int ni = 0; ni < 4; ++ni) {
                int n = wn + ni * 16 + row16;
                bfr[ni] = *reinterpret_cast<const bf16x8*>(&Bs[n * 64 + ((c8 ^ (n & 7)) * 8)]);
            }
            __builtin_amdgcn_s_setprio(1);
#pragma unroll
            for (int mi = 0; mi < 4; ++mi)
#pragma unroll
                for (int ni = 0; ni < 4; ++ni)
                    acc[mi][ni] = __builtin_amdgcn_mfma_f32_16x16x32_bf16(af[mi], bfr[ni], acc[mi][ni], 0, 0, 0);
            __builtin_amdgcn_s_setprio(0);
        }
    }

#pragma unroll
    for (int mi = 0; mi < 4; ++mi)
#pragma unroll
        for (int ni = 0; ni < 4; ++ni)
#pragma unroll
            for (int rr = 0; rr < 4; ++rr) {
                int rowg = mbase + wm + mi * 16 + grp * 4 + rr;
                int colg = nbase + wn + ni * 16 + row16;
                int b = rowg >> 11, t = rowg & (NT - 1);
                int h = colg >> 6, d = colg & 63;
                Out[((size_t)(b * NH + h) * NT + t) * DHD + d] = tobf(acc[mi][ni][rr] * oscale);
            }
}

// ---------------- K2: flash attention — round-16 config: 8 waves, KVB=128 ----------------
// Staging per tile: K = 2 reg-chunks/thread (all waves); V = quad-staging on waves 4-7.
__global__ __launch_bounds__(512)
void attn_kernel(const short* __restrict__ Qg, const short* __restrict__ Kg,
                 const short* __restrict__ Vg, short* __restrict__ An)
{
    __shared__ short Ks[KVB * 64];
    __shared__ short Vs[64 * KVB];

    const int tid = threadIdx.x;
    const int lane = tid & 63;
    const int wave = tid >> 6;       // 0..7
    const int l31 = lane & 31;
    const int h = lane >> 5;

    // id -> (head bh, q-block of 256): xcd = id&7 owns heads (id&7)*8 + (slot&7)
    const int id = blockIdx.x;       // 0..511
    const int slot = id >> 3;        // 0..63
    const int bh = (id & 7) * 8 + (slot & 7);
    const int qbase = (slot >> 3) * 256;

    const int b = bh >> 4, hh = bh & 15;
    const size_t headoff = (size_t)bh * NT * DHD;

    bf16x8 qf[4];
    {
        const short* qp = Qg + headoff + (size_t)(qbase + wave * 32 + l31) * DHD + h * 8;
#pragma unroll
        for (int ds = 0; ds < 4; ++ds)
            qf[ds] = *reinterpret_cast<const bf16x8*>(qp + ds * 16);
    }

    float l_run = 0.f;
    f32x16 o0 = (f32x16)0.f, o1 = (f32x16)0.f;

    bf16x8 Kst[2], Vst[4];
    const int tid2 = tid & 255;                 // V staging index for waves 4-7
    const int vi = tid2 & 31, vdc = tid2 >> 5;  // kv quad 4*vi.., d-chunk vdc

    // prologue: tile 0 -> regs
    {
        const short* Kp = Kg + headoff;
        const short* Vp = Vg + headoff;
#pragma unroll
        for (int it = 0; it < 2; ++it) {
            int chid = tid + it * 512;
            Kst[it] = *reinterpret_cast<const bf16x8*>(Kp + (size_t)(chid >> 3) * DHD + (chid & 7) * 8);
        }
        if (wave >= 4) {
#pragma unroll
            for (int s = 0; s < 4; ++s)
                Vst[s] = *reinterpret_cast<const bf16x8*>(Vp + (size_t)(4 * vi + s) * DHD + vdc * 8);
        }
    }

#define QKT(SACC, ST) do {                                                              \
        SACC = (f32x16)0.f;                                                             \
        __builtin_amdgcn_s_setprio(1);                                                  \
        _Pragma("unroll")                                                               \
        for (int ds = 0; ds < 4; ++ds) {                                                \
            int row_ = (ST) * 32 + l31;                                                 \
            int c8_ = ds * 2 + h;                                                       \
            bf16x8 kf_ = *reinterpret_cast<const bf16x8*>(                              \
                &Ks[row_ * 64 + ((c8_ ^ (row_ & 7)) * 8)]);                             \
            SACC = __builtin_amdgcn_mfma_f32_32x32x16_bf16(kf_, qf[ds], SACC, 0, 0, 0); \
        }                                                                               \
        __builtin_amdgcn_s_setprio(0);                                                  \
    } while (0)

#define SMPV(SACC, ST) do {                                                             \
        float p_[16];                                                                   \
        float rs_ = 0.f;                                                                \
        _Pragma("unroll")                                                               \
        for (int j = 0; j < 16; ++j) { p_[j] = fexp2(SACC[j]); rs_ += p_[j]; }          \
        l_run += rs_;                                                                   \
        union Pair_ { s16x4 v; int w[2]; };                                             \
        Pair_ quad_[2][2];                                                              \
        _Pragma("unroll")                                                               \
        for (int ks = 0; ks < 2; ++ks)                                                  \
            _Pragma("unroll")                                                           \
            for (int hd = 0; hd < 2; ++hd)                                              \
                _Pragma("unroll")                                                       \
                for (int e = 0; e < 4; ++e)                                             \
                    quad_[ks][hd].v[e] = tobf(p_[8 * ks + 4 * hd + e]);                 \
        bf16x8 pf_[2];                                                                  \
        _Pragma("unroll")                                                               \
        for (int ks = 0; ks < 2; ++ks) {                                                \
            Pair_ send_;                                                                \
            send_.v = h ? quad_[ks][0].v : quad_[ks][1].v;                              \
            Pair_ recv_;                                                                \
            recv_.w[0] = __shfl_xor(send_.w[0], 32);                                    \
            recv_.w[1] = __shfl_xor(send_.w[1], 32);                                    \
            Pair_ ownq_;                                                                \
            ownq_.v = h ? quad_[ks][1].v : quad_[ks][0].v;                              \
            union { struct { s16x4 lo, hi; } s; bf16x8 v; } u_;                         \
            u_.s.lo = h ? recv_.v : ownq_.v;                                            \
            u_.s.hi = h ? ownq_.v : recv_.v;                                            \
            pf_[ks] = u_.v;                                                             \
        }                                                                               \
        _Pragma("unroll")                                                               \
        for (int ks = 0; ks < 2; ++ks) {                                                \
            int ck_ = (ST) * 4 + ks * 2 + h;                                            \
            bf16x8 v0_ = *reinterpret_cast<const bf16x8*>(                              \
                &Vs[l31 * KVB + ((ck_ ^ (l31 & 7)) * 8)]);                              \
            bf16x8 v1_ = *reinterpret_cast<const bf16x8*>(                              \
                &Vs[(32 + l31) * KVB + ((ck_ ^ (l31 & 7)) * 8)]);                       \
            __builtin_amdgcn_s_setprio(1);                                              \
            o0 = __builtin_amdgcn_mfma_f32_32x32x16_bf16(pf_[ks], v0_, o0, 0, 0, 0);    \
            o1 = __builtin_amdgcn_mfma_f32_32x32x16_bf16(pf_[ks], v1_, o1, 0, 0, 0);    \
            __builtin_amdgcn_s_setprio(0);                                              \
        }                                                                               \
    } while (0)

    for (int kv = 0; kv < NT; kv += KVB) {
        // ---- (A): all reads of previous tile's LDS complete ----
        __builtin_amdgcn_sched_barrier(0);
        asm volatile("s_waitcnt lgkmcnt(0)" ::: "memory");
        __builtin_amdgcn_s_barrier();
        __builtin_amdgcn_sched_barrier(0);

        // commit staged regs -> LDS
#pragma unroll
        for (int it = 0; it < 2; ++it) {
            int chid = tid + it * 512;
            int row = chid >> 3, c8 = chid & 7;
            *reinterpret_cast<bf16x8*>(&Ks[row * 64 + ((c8 ^ (row & 7)) * 8)]) = Kst[it];
        }
        if (wave >= 4) {
#pragma unroll
            for (int e = 0; e < 8; ++e) {
                int d = vdc * 8 + e;
                s16x4 pk;
                pk[0] = Vst[0][e]; pk[1] = Vst[1][e]; pk[2] = Vst[2][e]; pk[3] = Vst[3][e];
                int kv4 = 4 * vi;
                *reinterpret_cast<s16x4*>(&Vs[d * KVB + (((kv4 >> 3) ^ (d & 7)) * 8) + (kv4 & 7)]) = pk;
            }
        }
        // issue next-tile loads (in flight across compute)
        if (kv + KVB < NT) {
            const short* Kp = Kg + headoff + (size_t)(kv + KVB) * DHD;
            const short* Vp = Vg + headoff + (size_t)(kv + KVB) * DHD;
#pragma unroll
            for (int it = 0; it < 2; ++it) {
                int chid = tid + it * 512;
                Kst[it] = *reinterpret_cast<const bf16x8*>(Kp + (size_t)(chid >> 3) * DHD + (chid & 7) * 8);
            }
            if (wave >= 4) {
#pragma unroll
                for (int s = 0; s < 4; ++s)
                    Vst[s] = *reinterpret_cast<const bf16x8*>(Vp + (size_t)(4 * vi + s) * DHD + vdc * 8);
            }
        }

        // ---- (B): staged LDS visible ----
        __builtin_amdgcn_sched_barrier(0);
        asm volatile("s_waitcnt lgkmcnt(0)" ::: "memory");
        __builtin_amdgcn_s_barrier();
        __builtin_amdgcn_sched_barrier(0);

        // ---- 2-deep pipeline over 4 subtiles ----
        f32x16 sA, sB;
        QKT(sA, 0);
        QKT(sB, 1);
        SMPV(sA, 0);
        QKT(sA, 2);
        SMPV(sB, 1);
        QKT(sB, 3);
        SMPV(sA, 2);
        SMPV(sB, 3);
    }
#undef QKT
#undef SMPV

    // ---- epilogue: merge half-sums, normalize, store ----
    float lt = l_run + __shfl_xor(l_run, 32);
    float linv = 1.0f / lt;
#pragma unroll
    for (int j = 0; j < 16; ++j) {
        int qr = (j & 3) + 8 * (j >> 2) + 4 * h;
        float lq = __shfl(linv, qr);
        int t = qbase + wave * 32 + qr;
        short* orow = An + (size_t)(b * NT + t) * ND + hh * DHD;
        orow[l31] = tobf(o0[j] * lq);
        orow[32 + l31] = tobf(o1[j] * lq);
    }
}

// ---------------- K3: output projection + bias (global_load_lds both sides) ----------------
__global__ __launch_bounds__(256, 4)
void outproj_kernel(const short* __restrict__ An, const short* __restrict__ Wot,
                    const float* __restrict__ bo, float* __restrict__ out)
{
    const int i = blockIdx.x;            // 0..511
    const int xcd = i & 7, c = i >> 3;
    const int by = xcd * 8 + (c >> 3);
    const int bx = c & 7;

    __shared__ short As[128 * 64];
    __shared__ short Bs[128 * 64];

    const int tid = threadIdx.x;
    const int lane = tid & 63;
    const int wave = tid >> 6;
    const int row16 = lane & 15;
    const int grp = lane >> 4;
    const int mbase = by * 128;
    const int nbase = bx * 128;
    const int wm = (wave >> 1) * 64;
    const int wn = (wave & 1) * 64;
    const int srcc = ((lane & 7) ^ (lane >> 3)) * 8;
    const int lrow = lane >> 3;

    f32x4 acc[4][4];
#pragma unroll
    for (int a = 0; a < 4; ++a)
#pragma unroll
        for (int bq = 0; bq < 4; ++bq) acc[a][bq] = (f32x4)0.0f;

    for (int kb = 0; kb < ND; kb += 64) {
        __syncthreads();
#pragma unroll
        for (int it = 0; it < 4; ++it) {
            int seg = wave * 4 + it;
            int row = seg * 8 + lrow;
            gload16(An  + (size_t)(mbase + row) * ND + kb + srcc, As + seg * 512);
            gload16(Wot + (size_t)(nbase + row) * ND + kb + srcc, Bs + seg * 512);
        }
        __syncthreads();

#pragma unroll
        for (int kk = 0; kk < 2; ++kk) {
            const int c8 = kk * 4 + grp;
            bf16x8 af[4], bfr[4];
#pragma unroll
            for (int mi = 0; mi < 4; ++mi) {
                int row = wm + mi * 16 + row16;
                af[mi] = *reinterpret_cast<const bf16x8*>(&As[row * 64 + ((c8 ^ (row & 7)) * 8)]);
            }
#pragma unroll
            for (int ni = 0; ni < 4; ++ni) {
                int n = wn + ni * 16 + row16;
                bfr[ni] = *reinterpret_cast<const bf16x8*>(&Bs[n * 64 + ((c8 ^ (n & 7)) * 8)]);
            }
            __builtin_amdgcn_s_setprio(1);
#pragma unroll
            for (int mi = 0; mi < 4; ++mi)
#pragma unroll
                for (int ni = 0; ni < 4; ++ni)
                    acc[mi][ni] = __builtin_amdgcn_mfma_f32_16x16x32_bf16(af[mi], bfr[ni], acc[mi][ni], 0, 0, 0);
            __builtin_amdgcn_s_setprio(0);
        }
    }

#pragma unroll
    for (int ni = 0; ni < 4; ++ni) {
        int colg = nbase + wn + ni * 16 + row16;
        float bv = bo[colg];
#pragma unroll
        for (int mi = 0; mi < 4; ++mi)
#pragma unroll
            for (int rr = 0; rr < 4; ++rr) {
                int rowg = mbase + wm + mi * 16 + grp * 4 + rr;
                out[(size_t)rowg * ND + colg] = acc[mi][ni][rr] + bv;
            }
    }
}

extern "C" void kernel_launch(void* const* d_in, const int* in_sizes, int n_in,
                              void* d_out, int out_size, void* d_ws, size_t ws_size,
                              hipStream_t stream) {
    const float* x  = (const float*)d_in[0];
    const float* Wq = (const float*)d_in[1];
    const float* Wk = (const float*)d_in[2];
    const float* Wv = (const float*)d_in[3];
    const float* Wo = (const float*)d_in[4];
    const float* bo = (const float*)d_in[5];
    float* out = (float*)d_out;

    const size_t HSZ = (size_t)NB * NH * NT * DHD;
    short* Q  = (short*)d_ws;
    short* K  = Q + HSZ;
    short* V  = K + HSZ;
    short* At = V + HSZ;   // attn output; holds xb before attn runs
    short* xb = At;        // x (bf16) — dead once attn overwrites At
    short* Wt4 = (short*)d_out;           // W^T bf16 x4 (8.4 MB) — d_out scratch, overwritten by out
    short* Wot = Wt4 + (size_t)3 * ND * ND;

    cvt_kernel<<<dim3((NB * NT * ND) / (256 * 8)), dim3(256), 0, stream>>>(x, xb);
    cvtw_kernel<<<dim3(8, 16, 4), dim3(256), 0, stream>>>(Wq, Wk, Wv, Wo, Wt4);
    qkv_kernel<<<dim3(3 * 8 * 64), dim3(256), 0, stream>>>(xb, Wt4, Q, K, V);
    attn_kernel<<<dim3(512), dim3(512), 0, stream>>>(Q, K, V, At);
    outproj_kernel<<<dim3(8 * 64), dim3(256), 0, stream>>>(At, Wot, bo, out);
}